// Round 7
// baseline (313.146 us; speedup 1.0000x reference)
//
#include <hip/hip_runtime.h>
#include <hip/hip_bf16.h>

typedef __attribute__((ext_vector_type(8))) short short8;
typedef __attribute__((ext_vector_type(4))) float float4_t;
typedef __attribute__((ext_vector_type(4))) _Float16 half4;

#define D_MODEL 1024
#define N_HEADS 16
#define HEAD_DIM 64
#define B_SZ 2
#define SEQ 2048
#define M_ROWS (B_SZ*SEQ)   // 4096
#define NQKV 3072
#define SC_LOG2E 0.18033688011112042f  // log2(e)/sqrt(HEAD_DIM)

__device__ __forceinline__ unsigned short f2bf(float f) {
  unsigned u = __float_as_uint(f);
  u += 0x7FFFu + ((u >> 16) & 1u);   // RNE
  return (unsigned short)(u >> 16);
}

__device__ __forceinline__ unsigned short f2h(float f) {
  _Float16 h = (_Float16)f;          // v_cvt_f16_f32, RNE
  return *(unsigned short*)&h;
}

// async global->LDS, 16B per lane. LDS base must be wave-uniform.
__device__ __forceinline__ void gl_lds16(const unsigned short* g, unsigned short* l) {
  __builtin_amdgcn_global_load_lds(
      (const __attribute__((address_space(1))) unsigned int*)(size_t)g,
      (__attribute__((address_space(3))) unsigned int*)(unsigned int)(size_t)l,
      16, 0, 0);
}

// ---- fused prep: x->bf16, Wp->bf16, Wq/Wk/Wv -> Wall [sel*1024+h*64+e][d] ----
__global__ void prep(const float* __restrict__ x, const float* __restrict__ Wp,
                     const float* __restrict__ Wq, const float* __restrict__ Wk,
                     const float* __restrict__ Wv,
                     unsigned short* __restrict__ xb, unsigned short* __restrict__ Wpb,
                     unsigned short* __restrict__ Wall) {
  __shared__ float t[16][17];
  int bid = blockIdx.x;
  if (bid < 5120) {
    const float* src; unsigned short* dst; int base;
    if (bid < 4096) { src = x;  dst = xb;  base = bid * 1024 + threadIdx.x * 4; }
    else            { src = Wp; dst = Wpb; base = (bid - 4096) * 1024 + threadIdx.x * 4; }
    float4 v = *(const float4*)(src + base);
    dst[base + 0] = f2bf(v.x);
    dst[base + 1] = f2bf(v.y);
    dst[base + 2] = f2bf(v.z);
    dst[base + 3] = f2bf(v.w);
  } else {
    int u = bid - 5120;
    int sel = u >> 12;
    u &= 4095;
    const float* W = sel == 0 ? Wq : (sel == 1 ? Wk : Wv);
    int d0 = (u & 63) * 16, e0 = ((u >> 6) & 3) * 16, hh = u >> 8;
    int tx = threadIdx.x & 15, ty = threadIdx.x >> 4;
    t[ty][tx] = W[hh * (D_MODEL * HEAD_DIM) + (d0 + ty) * HEAD_DIM + e0 + tx];
    __syncthreads();
    Wall[(size_t)(sel * 1024 + hh * 64 + e0 + ty) * D_MODEL + d0 + tx] = f2bf(t[tx][ty]);
  }
}

// ---- fused QKV: C[m][n] = xb[m,:] . Wall[n,:], coalesced epilogues ----
// Q pre-scaled by log2e/8 (bf16); K natural [b,h,s,e] (bf16);
// V 64x64-tiled in FP16: Vtb[(bh*32 + s/64)*4096 + e*64 + (s%64)]
__global__ __launch_bounds__(256) void qkv_gemm(const unsigned short* __restrict__ xb,
                                                const unsigned short* __restrict__ Wall,
                                                const float* __restrict__ bq,
                                                const float* __restrict__ bk,
                                                const float* __restrict__ bv,
                                                unsigned short* __restrict__ Qb,
                                                unsigned short* __restrict__ Kb,
                                                unsigned short* __restrict__ Vtb) {
  __shared__ unsigned short As[128 * 32], Bs[128 * 32];
  __shared__ __align__(16) unsigned short Stage[4][16 * 72];  // 1152 elem/wave
  const int m0 = blockIdx.x * 128, n0 = blockIdx.y * 128;
  const int lane = threadIdx.x & 63, w = threadIdx.x >> 6;
  const int l16 = lane & 15, quad = lane >> 4;
  const int wm = w & 1, wn = w >> 1;
  const int ldrow = lane >> 2, ldcol = (lane & 3) * 8;
  const unsigned short* ga0 = xb + (size_t)(m0 + w * 32 + ldrow) * D_MODEL + ldcol;
  const unsigned short* ga1 = ga0 + 16 * D_MODEL;
  const unsigned short* gb0 = Wall + (size_t)(n0 + w * 32 + ldrow) * D_MODEL + ldcol;
  const unsigned short* gb1 = gb0 + 16 * D_MODEL;
  unsigned short* lA0 = As + (w * 2 + 0) * 512;
  unsigned short* lA1 = As + (w * 2 + 1) * 512;
  unsigned short* lB0 = Bs + (w * 2 + 0) * 512;
  unsigned short* lB1 = Bs + (w * 2 + 1) * 512;
  float4_t acc[4][4];
  float4_t z = {0.f, 0.f, 0.f, 0.f};
#pragma unroll
  for (int i = 0; i < 4; i++)
#pragma unroll
    for (int j = 0; j < 4; j++) acc[i][j] = z;
  for (int k0 = 0; k0 < D_MODEL; k0 += 32) {
    __syncthreads();
    gl_lds16(ga0 + k0, lA0);
    gl_lds16(ga1 + k0, lA1);
    gl_lds16(gb0 + k0, lB0);
    gl_lds16(gb1 + k0, lB1);
    __syncthreads();
    short8 af[4], bf[4];
#pragma unroll
    for (int i = 0; i < 4; i++) af[i] = *(const short8*)&As[(wm * 64 + i * 16 + l16) * 32 + quad * 8];
#pragma unroll
    for (int j = 0; j < 4; j++) bf[j] = *(const short8*)&Bs[(wn * 64 + j * 16 + l16) * 32 + quad * 8];
#pragma unroll
    for (int i = 0; i < 4; i++)
#pragma unroll
      for (int j = 0; j < 4; j++)
        acc[i][j] = __builtin_amdgcn_mfma_f32_16x16x32_bf16(af[i], bf[j], acc[i][j], 0, 0, 0);
  }
  const int nb = n0 + wn * 64;       // 64-aligned -> sel, h wave-uniform
  const int sel = nb >> 10;
  const int h = (nb >> 6) & 15;
  const float* bias = sel == 0 ? bq : (sel == 1 ? bk : bv);
  const int mbase = m0 + wm * 64;
  const int bb = mbase >> 11;
  const size_t bh = (size_t)(bb * N_HEADS + h);
  if (sel == 2) {
    // V: transpose 64x64 C-tile through wave-private LDS -> coalesced 16B stores (fp16)
    unsigned short* vs = &Stage[w][0];
    const size_t vbase = bh * (32 * 4096) + (size_t)((mbase >> 6) & 31) * 4096;
    const int e8 = lane >> 3, ch = lane & 7;
#pragma unroll
    for (int j = 0; j < 4; j++) {
      float be = bias[h * 64 + j * 16 + l16];
#pragma unroll
      for (int i = 0; i < 4; i++)
#pragma unroll
        for (int r = 0; r < 4; r++)
          vs[l16 * 72 + i * 16 + quad * 4 + r] = f2h(acc[i][j][r] + be);
      // wave-private, DS in-order: no barrier
#pragma unroll
      for (int rd = 0; rd < 2; rd++) {
        int er = rd * 8 + e8;
        short8 val = *(const short8*)(vs + er * 72 + ch * 8);
        *(short8*)(Vtb + vbase + (size_t)(j * 16 + er) * 64 + ch * 8) = val;
      }
    }
  } else {
    // Q/K: stage [s][e] j-slice (64x16, stride 18) in wave-private LDS -> b128 stores
    unsigned short* st = &Stage[w][0];
    unsigned short* dst = (sel == 0) ? Qb : Kb;
    const float qsc = (sel == 0) ? SC_LOG2E : 1.0f;
    const size_t rowbase = bh * SEQ + (mbase & (SEQ - 1));
    const int r2 = lane >> 1, c2 = lane & 1;
#pragma unroll
    for (int j = 0; j < 4; j++) {
      float be = bias[h * 64 + j * 16 + l16];
#pragma unroll
      for (int i = 0; i < 4; i++)
#pragma unroll
        for (int r = 0; r < 4; r++)
          st[(i * 16 + quad * 4 + r) * 18 + l16] = f2bf((acc[i][j][r] + be) * qsc);
#pragma unroll
      for (int p = 0; p < 2; p++) {
        int row = p * 32 + r2;
        short8 val = *(const short8*)(st + row * 18 + c2 * 8);
        *(short8*)(dst + (rowbase + row) * HEAD_DIM + j * 16 + c2 * 8) = val;
      }
    }
  }
}

// ---- flash attention v7: LDS-free, barrier-free ----
// S^T = K.Q^T via 16x16x32 bf16 (K A-frags direct from global);
// P stays in registers (C-layout == A-layout of 16x16x16 f16); PV in fp16.
__global__ __launch_bounds__(256) void attn_kernel(const unsigned short* __restrict__ Q,
                                                   const unsigned short* __restrict__ K,
                                                   const unsigned short* __restrict__ Vt,
                                                   unsigned short* __restrict__ concat) {
  const int b = blockIdx.z, h = blockIdx.y;
  const int lane = threadIdx.x & 63, w = threadIdx.x >> 6;
  const int l16 = lane & 15, quad = lane >> 4;
  const size_t bh = (size_t)(b * N_HEADS + h);
  const int q0 = blockIdx.x * 128 + w * 32;
  float4_t z = {0.f, 0.f, 0.f, 0.f};

  // Q B-frags: B[k=e][n=q], lane n=l16, k=quad*8+j  (pre-scaled by log2e/8)
  short8 aq[2][2];
#pragma unroll
  for (int rg = 0; rg < 2; rg++)
#pragma unroll
    for (int hf = 0; hf < 2; hf++)
      aq[rg][hf] = *(const short8*)(Q + (bh * SEQ + q0 + rg * 16 + l16) * HEAD_DIM + hf * 32 + quad * 8);

  const unsigned short* kbase = K + bh * SEQ * HEAD_DIM;     // [t][e]
  const unsigned short* vbase = Vt + bh * (32 * 4096);       // 64x64 tiles, fp16

  float4_t o[2][4];   // O tiles: rows q=quad*4+r, cols e=l16 (per ne)
#pragma unroll
  for (int rg = 0; rg < 2; rg++)
#pragma unroll
    for (int ne = 0; ne < 4; ne++) o[rg][ne] = z;
  float lsp[2] = {0.f, 0.f};  // per-lane partial row-sum (q=l16, this quad's t)

  for (int it = 0; it < 32; ++it) {
    const unsigned short* kp = kbase + (size_t)it * 4096;    // 64 t-rows
    const unsigned short* vp = vbase + (size_t)it * 4096;    // one 64x64 tile
    // K A-frags: A[m=t][k=e], lane m=l16 (t within tc), k=quad*8+j
    short8 kf[4][2];
#pragma unroll
    for (int tc = 0; tc < 4; tc++)
#pragma unroll
      for (int hf = 0; hf < 2; hf++)
        kf[tc][hf] = *(const short8*)(kp + (tc * 16 + l16) * HEAD_DIM + hf * 32 + quad * 8);
    // V B-frags (fp16): B[k=t][n=e], lane n=l16 (e within ne), k=quad*4+j
    half4 vf[4][4];
#pragma unroll
    for (int tc = 0; tc < 4; tc++)
#pragma unroll
      for (int ne = 0; ne < 4; ne++)
        vf[tc][ne] = *(const half4*)(vp + (ne * 16 + l16) * 64 + tc * 16 + quad * 4);

#pragma unroll
    for (int tc = 0; tc < 4; tc++) {
#pragma unroll
      for (int rg = 0; rg < 2; rg++) {
        // S^T tile: rows t=quad*4+r, cols q=l16
        float4_t s = __builtin_amdgcn_mfma_f32_16x16x32_bf16(kf[tc][0], aq[rg][0], z, 0, 0, 0);
        s = __builtin_amdgcn_mfma_f32_16x16x32_bf16(kf[tc][1], aq[rg][1], s, 0, 0, 0);
        float p0 = __builtin_amdgcn_exp2f(s[0]);
        float p1 = __builtin_amdgcn_exp2f(s[1]);
        float p2 = __builtin_amdgcn_exp2f(s[2]);
        float p3 = __builtin_amdgcn_exp2f(s[3]);
        lsp[rg] += (p0 + p1) + (p2 + p3);
        half4 pa = {(_Float16)p0, (_Float16)p1, (_Float16)p2, (_Float16)p3};
        // PV: A[m=q][k=t]=pa (in-register!), B=vf -> O rows q, cols e
#pragma unroll
        for (int ne = 0; ne < 4; ne++)
          o[rg][ne] = __builtin_amdgcn_mfma_f32_16x16x16f16(pa, vf[tc][ne], o[rg][ne], 0, 0, 0);
      }
    }
  }

  // row-sums: reduce across quads (t-partials live at lane l16=q in each quad)
  float lsf[2];
#pragma unroll
  for (int rg = 0; rg < 2; rg++) {
    float v = lsp[rg];
    v += __shfl_xor(v, 16, 64);
    v += __shfl_xor(v, 32, 64);
    lsf[rg] = v;   // every lane with same l16 now has full sum for q=l16
  }
#pragma unroll
  for (int rg = 0; rg < 2; rg++) {
#pragma unroll
    for (int r = 0; r < 4; r++) {
      float li = 1.0f / __shfl(lsf[rg], quad * 4 + r, 64);  // sum for q=quad*4+r
      int sr = q0 + rg * 16 + quad * 4 + r;
#pragma unroll
      for (int ne = 0; ne < 4; ne++)
        concat[((size_t)(b * SEQ + sr)) * D_MODEL + h * 64 + ne * 16 + l16] = f2bf(o[rg][ne][r] * li);
    }
  }
}

// ---- out = concat @ Wp^T + bp (f32 out), 128x64 tiles -> 512 blocks ----
__global__ __launch_bounds__(256) void out_gemm(const unsigned short* __restrict__ cb,
                                                const unsigned short* __restrict__ Wpb,
                                                const float* __restrict__ bp,
                                                float* __restrict__ out) {
  __shared__ unsigned short As[128 * 32], Bs[64 * 32];
  const int m0 = blockIdx.x * 128, n0 = blockIdx.y * 64;
  const int lane = threadIdx.x & 63, w = threadIdx.x >> 6;
  const int l16 = lane & 15, quad = lane >> 4;
  const int ldrow = lane >> 2, ldcol = (lane & 3) * 8;
  const unsigned short* ga0 = cb + (size_t)(m0 + w * 32 + ldrow) * D_MODEL + ldcol;
  const unsigned short* ga1 = ga0 + 16 * D_MODEL;
  const unsigned short* gb0 = Wpb + (size_t)(n0 + w * 16 + ldrow) * D_MODEL + ldcol;
  unsigned short* lA0 = As + (w * 2 + 0) * 512;
  unsigned short* lA1 = As + (w * 2 + 1) * 512;
  unsigned short* lB0 = Bs + w * 512;
  float4_t acc[2][4];
  float4_t z = {0.f, 0.f, 0.f, 0.f};
#pragma unroll
  for (int i = 0; i < 2; i++)
#pragma unroll
    for (int j = 0; j < 4; j++) acc[i][j] = z;
  for (int k0 = 0; k0 < D_MODEL; k0 += 32) {
    __syncthreads();
    gl_lds16(ga0 + k0, lA0);
    gl_lds16(ga1 + k0, lA1);
    gl_lds16(gb0 + k0, lB0);
    __syncthreads();
    short8 af[2], bf[4];
#pragma unroll
    for (int i = 0; i < 2; i++) af[i] = *(const short8*)&As[(w * 32 + i * 16 + l16) * 32 + quad * 8];
#pragma unroll
    for (int j = 0; j < 4; j++) bf[j] = *(const short8*)&Bs[(j * 16 + l16) * 32 + quad * 8];
#pragma unroll
    for (int i = 0; i < 2; i++)
#pragma unroll
      for (int j = 0; j < 4; j++)
        acc[i][j] = __builtin_amdgcn_mfma_f32_16x16x32_bf16(af[i], bf[j], acc[i][j], 0, 0, 0);
  }
#pragma unroll
  for (int i = 0; i < 2; i++)
#pragma unroll
    for (int j = 0; j < 4; j++)
#pragma unroll
      for (int r = 0; r < 4; r++) {
        int m = m0 + w * 32 + i * 16 + quad * 4 + r;
        int oc = n0 + j * 16 + l16;
        out[(size_t)m * D_MODEL + oc] = acc[i][j][r] + bp[oc];
      }
}

extern "C" void kernel_launch(void* const* d_in, const int* in_sizes, int n_in,
                              void* d_out, int out_size, void* d_ws, size_t ws_size,
                              hipStream_t stream) {
  const float* x  = (const float*)d_in[0];
  const float* Wq = (const float*)d_in[1];
  const float* Wk = (const float*)d_in[2];
  const float* Wv = (const float*)d_in[3];
  const float* bq = (const float*)d_in[4];
  const float* bk = (const float*)d_in[5];
  const float* bv = (const float*)d_in[6];
  const float* Wp = (const float*)d_in[7];
  const float* bp = (const float*)d_in[8];
  float* out = (float*)d_out;

  char* ws = (char*)d_ws;
  size_t off = 0;
  auto alloc = [&](size_t bytes) -> void* {
    void* p = ws + off;
    off += (bytes + 255) & ~(size_t)255;
    return p;
  };
  unsigned short* xb   = (unsigned short*)alloc((size_t)M_ROWS * D_MODEL * 2);
  unsigned short* Wall = (unsigned short*)alloc((size_t)NQKV * D_MODEL * 2);
  unsigned short* Wpb  = (unsigned short*)alloc((size_t)D_MODEL * D_MODEL * 2);
  unsigned short* Qb   = (unsigned short*)alloc((size_t)B_SZ * N_HEADS * SEQ * HEAD_DIM * 2);
  unsigned short* Kb   = (unsigned short*)alloc((size_t)B_SZ * N_HEADS * SEQ * HEAD_DIM * 2);
  unsigned short* Vtb  = (unsigned short*)alloc((size_t)B_SZ * N_HEADS * SEQ * HEAD_DIM * 2);
  unsigned short* cbuf = (unsigned short*)alloc((size_t)B_SZ * SEQ * D_MODEL * 2);

  prep<<<17408, 256, 0, stream>>>(x, Wp, Wq, Wk, Wv, xb, Wpb, Wall);

  qkv_gemm<<<dim3(M_ROWS / 128, NQKV / 128), 256, 0, stream>>>(xb, Wall, bq, bk, bv, Qb, Kb, Vtb);

  attn_kernel<<<dim3(SEQ / 128, N_HEADS, B_SZ), 256, 0, stream>>>(Qb, Kb, Vtb, cbuf);

  out_gemm<<<dim3(M_ROWS / 128, D_MODEL / 64), 256, 0, stream>>>(cbuf, Wpb, bp, out);
}

// Round 8
// 194.537 us; speedup vs baseline: 1.6097x; 1.6097x over previous
//
#include <hip/hip_runtime.h>
#include <hip/hip_bf16.h>

typedef __attribute__((ext_vector_type(8))) short short8;
typedef __attribute__((ext_vector_type(4))) float float4_t;
typedef __attribute__((ext_vector_type(4))) _Float16 half4;

#define D_MODEL 1024
#define N_HEADS 16
#define HEAD_DIM 64
#define B_SZ 2
#define SEQ 2048
#define M_ROWS (B_SZ*SEQ)   // 4096
#define NQKV 3072
#define SC_LOG2E 0.18033688011112042f  // log2(e)/sqrt(HEAD_DIM)

__device__ __forceinline__ unsigned short f2bf(float f) {
  unsigned u = __float_as_uint(f);
  u += 0x7FFFu + ((u >> 16) & 1u);   // RNE
  return (unsigned short)(u >> 16);
}

__device__ __forceinline__ unsigned short f2h(float f) {
  _Float16 h = (_Float16)f;          // v_cvt_f16_f32, RNE
  return *(unsigned short*)&h;
}

// async global->LDS, 16B per lane. LDS base must be wave-uniform.
__device__ __forceinline__ void gl_lds16(const unsigned short* g, unsigned short* l) {
  __builtin_amdgcn_global_load_lds(
      (const __attribute__((address_space(1))) unsigned int*)(size_t)g,
      (__attribute__((address_space(3))) unsigned int*)(unsigned int)(size_t)l,
      16, 0, 0);
}

// ---- fused prep: x->bf16, Wp->bf16, Wq/Wk/Wv -> Wall [sel*1024+h*64+e][d] ----
__global__ void prep(const float* __restrict__ x, const float* __restrict__ Wp,
                     const float* __restrict__ Wq, const float* __restrict__ Wk,
                     const float* __restrict__ Wv,
                     unsigned short* __restrict__ xb, unsigned short* __restrict__ Wpb,
                     unsigned short* __restrict__ Wall) {
  __shared__ float t[16][17];
  int bid = blockIdx.x;
  if (bid < 5120) {
    const float* src; unsigned short* dst; int base;
    if (bid < 4096) { src = x;  dst = xb;  base = bid * 1024 + threadIdx.x * 4; }
    else            { src = Wp; dst = Wpb; base = (bid - 4096) * 1024 + threadIdx.x * 4; }
    float4 v = *(const float4*)(src + base);
    dst[base + 0] = f2bf(v.x);
    dst[base + 1] = f2bf(v.y);
    dst[base + 2] = f2bf(v.z);
    dst[base + 3] = f2bf(v.w);
  } else {
    int u = bid - 5120;
    int sel = u >> 12;
    u &= 4095;
    const float* W = sel == 0 ? Wq : (sel == 1 ? Wk : Wv);
    int d0 = (u & 63) * 16, e0 = ((u >> 6) & 3) * 16, hh = u >> 8;
    int tx = threadIdx.x & 15, ty = threadIdx.x >> 4;
    t[ty][tx] = W[hh * (D_MODEL * HEAD_DIM) + (d0 + ty) * HEAD_DIM + e0 + tx];
    __syncthreads();
    Wall[(size_t)(sel * 1024 + hh * 64 + e0 + ty) * D_MODEL + d0 + tx] = f2bf(t[tx][ty]);
  }
}

// ---- fused QKV: C[m][n] = xb[m,:] . Wall[n,:], coalesced epilogues ----
// Q pre-scaled by log2e/8 (bf16); K natural [b,h,s,e] (bf16);
// V 64x64-tiled in FP16: Vtb[(bh*32 + s/64)*4096 + e*64 + (s%64)]
__global__ __launch_bounds__(256) void qkv_gemm(const unsigned short* __restrict__ xb,
                                                const unsigned short* __restrict__ Wall,
                                                const float* __restrict__ bq,
                                                const float* __restrict__ bk,
                                                const float* __restrict__ bv,
                                                unsigned short* __restrict__ Qb,
                                                unsigned short* __restrict__ Kb,
                                                unsigned short* __restrict__ Vtb) {
  __shared__ unsigned short As[128 * 32], Bs[128 * 32];
  __shared__ __align__(16) unsigned short Stage[4][16 * 72];  // 1152 elem/wave
  const int m0 = blockIdx.x * 128, n0 = blockIdx.y * 128;
  const int lane = threadIdx.x & 63, w = threadIdx.x >> 6;
  const int l16 = lane & 15, quad = lane >> 4;
  const int wm = w & 1, wn = w >> 1;
  const int ldrow = lane >> 2, ldcol = (lane & 3) * 8;
  const unsigned short* ga0 = xb + (size_t)(m0 + w * 32 + ldrow) * D_MODEL + ldcol;
  const unsigned short* ga1 = ga0 + 16 * D_MODEL;
  const unsigned short* gb0 = Wall + (size_t)(n0 + w * 32 + ldrow) * D_MODEL + ldcol;
  const unsigned short* gb1 = gb0 + 16 * D_MODEL;
  unsigned short* lA0 = As + (w * 2 + 0) * 512;
  unsigned short* lA1 = As + (w * 2 + 1) * 512;
  unsigned short* lB0 = Bs + (w * 2 + 0) * 512;
  unsigned short* lB1 = Bs + (w * 2 + 1) * 512;
  float4_t acc[4][4];
  float4_t z = {0.f, 0.f, 0.f, 0.f};
#pragma unroll
  for (int i = 0; i < 4; i++)
#pragma unroll
    for (int j = 0; j < 4; j++) acc[i][j] = z;
  for (int k0 = 0; k0 < D_MODEL; k0 += 32) {
    __syncthreads();
    gl_lds16(ga0 + k0, lA0);
    gl_lds16(ga1 + k0, lA1);
    gl_lds16(gb0 + k0, lB0);
    gl_lds16(gb1 + k0, lB1);
    __syncthreads();
    short8 af[4], bf[4];
#pragma unroll
    for (int i = 0; i < 4; i++) af[i] = *(const short8*)&As[(wm * 64 + i * 16 + l16) * 32 + quad * 8];
#pragma unroll
    for (int j = 0; j < 4; j++) bf[j] = *(const short8*)&Bs[(wn * 64 + j * 16 + l16) * 32 + quad * 8];
#pragma unroll
    for (int i = 0; i < 4; i++)
#pragma unroll
      for (int j = 0; j < 4; j++)
        acc[i][j] = __builtin_amdgcn_mfma_f32_16x16x32_bf16(af[i], bf[j], acc[i][j], 0, 0, 0);
  }
  const int nb = n0 + wn * 64;       // 64-aligned -> sel, h wave-uniform
  const int sel = nb >> 10;
  const int h = (nb >> 6) & 15;
  const float* bias = sel == 0 ? bq : (sel == 1 ? bk : bv);
  const int mbase = m0 + wm * 64;
  const int bb = mbase >> 11;
  const size_t bh = (size_t)(bb * N_HEADS + h);
  if (sel == 2) {
    // V: transpose 64x64 C-tile through wave-private LDS -> coalesced 16B stores (fp16)
    unsigned short* vs = &Stage[w][0];
    const size_t vbase = bh * (32 * 4096) + (size_t)((mbase >> 6) & 31) * 4096;
    const int e8 = lane >> 3, ch = lane & 7;
#pragma unroll
    for (int j = 0; j < 4; j++) {
      float be = bias[h * 64 + j * 16 + l16];
#pragma unroll
      for (int i = 0; i < 4; i++)
#pragma unroll
        for (int r = 0; r < 4; r++)
          vs[l16 * 72 + i * 16 + quad * 4 + r] = f2h(acc[i][j][r] + be);
      // wave-private, DS in-order: no barrier
#pragma unroll
      for (int rd = 0; rd < 2; rd++) {
        int er = rd * 8 + e8;
        short8 val = *(const short8*)(vs + er * 72 + ch * 8);
        *(short8*)(Vtb + vbase + (size_t)(j * 16 + er) * 64 + ch * 8) = val;
      }
    }
  } else {
    // Q/K: stage [s][e] j-slice (64x16, stride 18) in wave-private LDS -> b128 stores
    unsigned short* st = &Stage[w][0];
    unsigned short* dst = (sel == 0) ? Qb : Kb;
    const float qsc = (sel == 0) ? SC_LOG2E : 1.0f;
    const size_t rowbase = bh * SEQ + (mbase & (SEQ - 1));
    const int r2 = lane >> 1, c2 = lane & 1;
#pragma unroll
    for (int j = 0; j < 4; j++) {
      float be = bias[h * 64 + j * 16 + l16];
#pragma unroll
      for (int i = 0; i < 4; i++)
#pragma unroll
        for (int r = 0; r < 4; r++)
          st[(i * 16 + quad * 4 + r) * 18 + l16] = f2bf((acc[i][j][r] + be) * qsc);
#pragma unroll
      for (int p = 0; p < 2; p++) {
        int row = p * 32 + r2;
        short8 val = *(const short8*)(st + row * 18 + c2 * 8);
        *(short8*)(dst + (rowbase + row) * HEAD_DIM + j * 16 + c2 * 8) = val;
      }
    }
  }
}

// ---- flash attention v8: K/V LDS double-buffer + register-resident P ----
// 128 threads = 2 waves x 64 Q-rows. S^T = K.Q^T (K A-frags from LDS);
// P converts in-register to f16 A-frags (C-layout == A-layout identity, r7-verified);
// PV via 16x16x16 f16 with V B-frags from LDS (fp16).
__global__ __launch_bounds__(128) void attn_kernel(const unsigned short* __restrict__ Q,
                                                   const unsigned short* __restrict__ K,
                                                   const unsigned short* __restrict__ Vt,
                                                   unsigned short* __restrict__ concat) {
  __shared__ __align__(16) unsigned short Ks0[64 * 72], Ks1[64 * 72];
  __shared__ __align__(16) unsigned short Vs0[64 * 72], Vs1[64 * 72];
  const int b = blockIdx.z, h = blockIdx.y;
  const int lane = threadIdx.x & 63, w = threadIdx.x >> 6;  // w in {0,1}
  const int l16 = lane & 15, quad = lane >> 4;
  const size_t bh = (size_t)(b * N_HEADS + h);
  const int q0 = blockIdx.x * 128 + w * 64;
  float4_t z = {0.f, 0.f, 0.f, 0.f};

  // Q B-frags: B[k=e][n=q], lane n=l16 -> q=rg*16+l16, k=quad*8+j (pre-scaled)
  short8 aq[4][2];
#pragma unroll
  for (int rg = 0; rg < 4; rg++)
#pragma unroll
    for (int hf = 0; hf < 2; hf++)
      aq[rg][hf] = *(const short8*)(Q + (bh * SEQ + q0 + rg * 16 + l16) * HEAD_DIM + hf * 32 + quad * 8);

  // staging: wave w stages rows w*32 + s*8 + srow (s=0..3) of K and V tiles
  const int srow = lane >> 3, schk = lane & 7;
  const unsigned short* kg = K + (bh * SEQ + w * 32 + srow) * HEAD_DIM + schk * 8;
  const unsigned short* vg = Vt + bh * (32 * 4096) + (w * 32 + srow) * 64 + schk * 8;
  const int wr = (w * 32 + srow) * 72 + schk * 8;

  float4_t o[4][4];
#pragma unroll
  for (int rg = 0; rg < 4; rg++)
#pragma unroll
    for (int ne = 0; ne < 4; ne++) o[rg][ne] = z;
  float lsp[4] = {0.f, 0.f, 0.f, 0.f};

  short8 kreg[4], vreg[4];
#pragma unroll
  for (int s = 0; s < 4; s++) {
    kreg[s] = *(const short8*)(kg + s * 512);
    vreg[s] = *(const short8*)(vg + s * 512);
  }
  kg += 4096; vg += 4096;

  auto step = [&](unsigned short* kb, unsigned short* vb, int itv) {
#pragma unroll
    for (int s = 0; s < 4; s++) {
      *(short8*)(kb + wr + s * 576) = kreg[s];
      *(short8*)(vb + wr + s * 576) = vreg[s];
    }
    __syncthreads();
    if (itv < 31) {
#pragma unroll
      for (int s = 0; s < 4; s++) {
        kreg[s] = *(const short8*)(kg + s * 512);
        vreg[s] = *(const short8*)(vg + s * 512);
      }
      kg += 4096; vg += 4096;
    }
#pragma unroll
    for (int tc = 0; tc < 4; tc++) {
      // K A-frags: A[m=t=tc*16+l16][k=e=hf*32+quad*8+j]
      short8 kf0 = *(const short8*)(kb + (tc * 16 + l16) * 72 + quad * 8);
      short8 kf1 = *(const short8*)(kb + (tc * 16 + l16) * 72 + 32 + quad * 8);
      // V B-frags (f16): B[k=t=tc*16+quad*4+j][n=e=ne*16+l16]
      half4 vf[4];
#pragma unroll
      for (int ne = 0; ne < 4; ne++)
        vf[ne] = *(const half4*)(vb + (ne * 16 + l16) * 72 + tc * 16 + quad * 4);
#pragma unroll
      for (int rg = 0; rg < 4; rg++) {
        float4_t s = __builtin_amdgcn_mfma_f32_16x16x32_bf16(kf0, aq[rg][0], z, 0, 0, 0);
        s = __builtin_amdgcn_mfma_f32_16x16x32_bf16(kf1, aq[rg][1], s, 0, 0, 0);
        float p0 = __builtin_amdgcn_exp2f(s[0]);
        float p1 = __builtin_amdgcn_exp2f(s[1]);
        float p2 = __builtin_amdgcn_exp2f(s[2]);
        float p3 = __builtin_amdgcn_exp2f(s[3]);
        lsp[rg] += (p0 + p1) + (p2 + p3);
        half4 pa = {(_Float16)p0, (_Float16)p1, (_Float16)p2, (_Float16)p3};
#pragma unroll
        for (int ne = 0; ne < 4; ne++)
          o[rg][ne] = __builtin_amdgcn_mfma_f32_16x16x16f16(pa, vf[ne], o[rg][ne], 0, 0, 0);
      }
    }
  };

  for (int it2 = 0; it2 < 16; ++it2) {
    step(Ks0, Vs0, 2 * it2);
    step(Ks1, Vs1, 2 * it2 + 1);
  }

  // row-sums: lsp holds per-quad t-partials for q=l16; reduce across quads
  float lsf[4];
#pragma unroll
  for (int rg = 0; rg < 4; rg++) {
    float v = lsp[rg];
    v += __shfl_xor(v, 16, 64);
    v += __shfl_xor(v, 32, 64);
    lsf[rg] = v;
  }
#pragma unroll
  for (int rg = 0; rg < 4; rg++) {
#pragma unroll
    for (int r = 0; r < 4; r++) {
      float li = 1.0f / __shfl(lsf[rg], quad * 4 + r, 64);
      int sr = q0 + rg * 16 + quad * 4 + r;
#pragma unroll
      for (int ne = 0; ne < 4; ne++)
        concat[((size_t)(b * SEQ + sr)) * D_MODEL + h * 64 + ne * 16 + l16] = f2bf(o[rg][ne][r] * li);
    }
  }
}

// ---- out = concat @ Wp^T + bp (f32 out), 128x64 tiles -> 512 blocks ----
__global__ __launch_bounds__(256) void out_gemm(const unsigned short* __restrict__ cb,
                                                const unsigned short* __restrict__ Wpb,
                                                const float* __restrict__ bp,
                                                float* __restrict__ out) {
  __shared__ unsigned short As[128 * 32], Bs[64 * 32];
  const int m0 = blockIdx.x * 128, n0 = blockIdx.y * 64;
  const int lane = threadIdx.x & 63, w = threadIdx.x >> 6;
  const int l16 = lane & 15, quad = lane >> 4;
  const int ldrow = lane >> 2, ldcol = (lane & 3) * 8;
  const unsigned short* ga0 = cb + (size_t)(m0 + w * 32 + ldrow) * D_MODEL + ldcol;
  const unsigned short* ga1 = ga0 + 16 * D_MODEL;
  const unsigned short* gb0 = Wpb + (size_t)(n0 + w * 16 + ldrow) * D_MODEL + ldcol;
  unsigned short* lA0 = As + (w * 2 + 0) * 512;
  unsigned short* lA1 = As + (w * 2 + 1) * 512;
  unsigned short* lB0 = Bs + w * 512;
  float4_t acc[2][4];
  float4_t z = {0.f, 0.f, 0.f, 0.f};
#pragma unroll
  for (int i = 0; i < 2; i++)
#pragma unroll
    for (int j = 0; j < 4; j++) acc[i][j] = z;
  for (int k0 = 0; k0 < D_MODEL; k0 += 32) {
    __syncthreads();
    gl_lds16(ga0 + k0, lA0);
    gl_lds16(ga1 + k0, lA1);
    gl_lds16(gb0 + k0, lB0);
    __syncthreads();
    short8 af[2], bf[4];
#pragma unroll
    for (int i = 0; i < 2; i++) af[i] = *(const short8*)&As[(w * 32 + i * 16 + l16) * 32 + quad * 8];
#pragma unroll
    for (int j = 0; j < 4; j++) bf[j] = *(const short8*)&Bs[(j * 16 + l16) * 32 + quad * 8];
#pragma unroll
    for (int i = 0; i < 2; i++)
#pragma unroll
      for (int j = 0; j < 4; j++)
        acc[i][j] = __builtin_amdgcn_mfma_f32_16x16x32_bf16(af[i], bf[j], acc[i][j], 0, 0, 0);
  }
#pragma unroll
  for (int i = 0; i < 2; i++)
#pragma unroll
    for (int j = 0; j < 4; j++)
#pragma unroll
      for (int r = 0; r < 4; r++) {
        int m = m0 + w * 32 + i * 16 + quad * 4 + r;
        int oc = n0 + j * 16 + l16;
        out[(size_t)m * D_MODEL + oc] = acc[i][j][r] + bp[oc];
      }
}

extern "C" void kernel_launch(void* const* d_in, const int* in_sizes, int n_in,
                              void* d_out, int out_size, void* d_ws, size_t ws_size,
                              hipStream_t stream) {
  const float* x  = (const float*)d_in[0];
  const float* Wq = (const float*)d_in[1];
  const float* Wk = (const float*)d_in[2];
  const float* Wv = (const float*)d_in[3];
  const float* bq = (const float*)d_in[4];
  const float* bk = (const float*)d_in[5];
  const float* bv = (const float*)d_in[6];
  const float* Wp = (const float*)d_in[7];
  const float* bp = (const float*)d_in[8];
  float* out = (float*)d_out;

  char* ws = (char*)d_ws;
  size_t off = 0;
  auto alloc = [&](size_t bytes) -> void* {
    void* p = ws + off;
    off += (bytes + 255) & ~(size_t)255;
    return p;
  };
  unsigned short* xb   = (unsigned short*)alloc((size_t)M_ROWS * D_MODEL * 2);
  unsigned short* Wall = (unsigned short*)alloc((size_t)NQKV * D_MODEL * 2);
  unsigned short* Wpb  = (unsigned short*)alloc((size_t)D_MODEL * D_MODEL * 2);
  unsigned short* Qb   = (unsigned short*)alloc((size_t)B_SZ * N_HEADS * SEQ * HEAD_DIM * 2);
  unsigned short* Kb   = (unsigned short*)alloc((size_t)B_SZ * N_HEADS * SEQ * HEAD_DIM * 2);
  unsigned short* Vtb  = (unsigned short*)alloc((size_t)B_SZ * N_HEADS * SEQ * HEAD_DIM * 2);
  unsigned short* cbuf = (unsigned short*)alloc((size_t)B_SZ * SEQ * D_MODEL * 2);

  prep<<<17408, 256, 0, stream>>>(x, Wp, Wq, Wk, Wv, xb, Wpb, Wall);

  qkv_gemm<<<dim3(M_ROWS / 128, NQKV / 128), 256, 0, stream>>>(xb, Wall, bq, bk, bv, Qb, Kb, Vtb);

  attn_kernel<<<dim3(SEQ / 128, N_HEADS, B_SZ), 128, 0, stream>>>(Qb, Kb, Vtb, cbuf);

  out_gemm<<<dim3(M_ROWS / 128, D_MODEL / 64), 256, 0, stream>>>(cbuf, Wpb, bp, out);
}

// Round 10
// 188.713 us; speedup vs baseline: 1.6594x; 1.0309x over previous
//
#include <hip/hip_runtime.h>
#include <hip/hip_bf16.h>

typedef __attribute__((ext_vector_type(8))) short short8;
typedef __attribute__((ext_vector_type(4))) short svec4;
typedef __attribute__((ext_vector_type(4))) float float4_t;
typedef __attribute__((ext_vector_type(8))) _Float16 half8;

#define D_MODEL 1024
#define N_HEADS 16
#define HEAD_DIM 64
#define B_SZ 2
#define SEQ 2048
#define M_ROWS (B_SZ*SEQ)   // 4096
#define NQKV 3072
#define SC_LOG2E 0.18033688011112042f  // log2(e)/sqrt(HEAD_DIM)

__device__ __forceinline__ unsigned short f2bf(float f) {
  unsigned u = __float_as_uint(f);
  u += 0x7FFFu + ((u >> 16) & 1u);   // RNE
  return (unsigned short)(u >> 16);
}

__device__ __forceinline__ unsigned short f2h(float f) {
  _Float16 h = (_Float16)f;          // v_cvt_f16_f32, RNE
  return *(unsigned short*)&h;
}

// async global->LDS, 16B per lane. LDS base must be wave-uniform.
__device__ __forceinline__ void gl_lds16(const unsigned short* g, unsigned short* l) {
  __builtin_amdgcn_global_load_lds(
      (const __attribute__((address_space(1))) unsigned int*)(size_t)g,
      (__attribute__((address_space(3))) unsigned int*)(unsigned int)(size_t)l,
      16, 0, 0);
}

// ---- fused prep: x->bf16, Wp->bf16, Wq/Wk/Wv -> Wall [sel*1024+h*64+e][d] ----
__global__ void prep(const float* __restrict__ x, const float* __restrict__ Wp,
                     const float* __restrict__ Wq, const float* __restrict__ Wk,
                     const float* __restrict__ Wv,
                     unsigned short* __restrict__ xb, unsigned short* __restrict__ Wpb,
                     unsigned short* __restrict__ Wall) {
  __shared__ float t[16][17];
  int bid = blockIdx.x;
  if (bid < 5120) {
    const float* src; unsigned short* dst; int base;
    if (bid < 4096) { src = x;  dst = xb;  base = bid * 1024 + threadIdx.x * 4; }
    else            { src = Wp; dst = Wpb; base = (bid - 4096) * 1024 + threadIdx.x * 4; }
    float4 v = *(const float4*)(src + base);
    dst[base + 0] = f2bf(v.x);
    dst[base + 1] = f2bf(v.y);
    dst[base + 2] = f2bf(v.z);
    dst[base + 3] = f2bf(v.w);
  } else {
    int u = bid - 5120;
    int sel = u >> 12;
    u &= 4095;
    const float* W = sel == 0 ? Wq : (sel == 1 ? Wk : Wv);
    int d0 = (u & 63) * 16, e0 = ((u >> 6) & 3) * 16, hh = u >> 8;
    int tx = threadIdx.x & 15, ty = threadIdx.x >> 4;
    t[ty][tx] = W[hh * (D_MODEL * HEAD_DIM) + (d0 + ty) * HEAD_DIM + e0 + tx];
    __syncthreads();
    Wall[(size_t)(sel * 1024 + hh * 64 + e0 + ty) * D_MODEL + d0 + tx] = f2bf(t[tx][ty]);
  }
}

// ---- fused QKV: C[m][n] = xb[m,:] . Wall[n,:], coalesced epilogues ----
// Q pre-scaled by log2e/8 (bf16); K natural [b,h,s,e] (bf16);
// V 64x64-tiled in FP16: Vtb[(bh*32 + s/64)*4096 + e*64 + (s%64)]
__global__ __launch_bounds__(256) void qkv_gemm(const unsigned short* __restrict__ xb,
                                                const unsigned short* __restrict__ Wall,
                                                const float* __restrict__ bq,
                                                const float* __restrict__ bk,
                                                const float* __restrict__ bv,
                                                unsigned short* __restrict__ Qb,
                                                unsigned short* __restrict__ Kb,
                                                unsigned short* __restrict__ Vtb) {
  __shared__ unsigned short As[128 * 32], Bs[128 * 32];
  __shared__ __align__(16) unsigned short Stage[4][16 * 72];  // 1152 elem/wave
  const int m0 = blockIdx.x * 128, n0 = blockIdx.y * 128;
  const int lane = threadIdx.x & 63, w = threadIdx.x >> 6;
  const int l16 = lane & 15, quad = lane >> 4;
  const int wm = w & 1, wn = w >> 1;
  const int ldrow = lane >> 2, ldcol = (lane & 3) * 8;
  const unsigned short* ga0 = xb + (size_t)(m0 + w * 32 + ldrow) * D_MODEL + ldcol;
  const unsigned short* ga1 = ga0 + 16 * D_MODEL;
  const unsigned short* gb0 = Wall + (size_t)(n0 + w * 32 + ldrow) * D_MODEL + ldcol;
  const unsigned short* gb1 = gb0 + 16 * D_MODEL;
  unsigned short* lA0 = As + (w * 2 + 0) * 512;
  unsigned short* lA1 = As + (w * 2 + 1) * 512;
  unsigned short* lB0 = Bs + (w * 2 + 0) * 512;
  unsigned short* lB1 = Bs + (w * 2 + 1) * 512;
  float4_t acc[4][4];
  float4_t z = {0.f, 0.f, 0.f, 0.f};
#pragma unroll
  for (int i = 0; i < 4; i++)
#pragma unroll
    for (int j = 0; j < 4; j++) acc[i][j] = z;
  for (int k0 = 0; k0 < D_MODEL; k0 += 32) {
    __syncthreads();
    gl_lds16(ga0 + k0, lA0);
    gl_lds16(ga1 + k0, lA1);
    gl_lds16(gb0 + k0, lB0);
    gl_lds16(gb1 + k0, lB1);
    __syncthreads();
    short8 af[4], bf[4];
#pragma unroll
    for (int i = 0; i < 4; i++) af[i] = *(const short8*)&As[(wm * 64 + i * 16 + l16) * 32 + quad * 8];
#pragma unroll
    for (int j = 0; j < 4; j++) bf[j] = *(const short8*)&Bs[(wn * 64 + j * 16 + l16) * 32 + quad * 8];
#pragma unroll
    for (int i = 0; i < 4; i++)
#pragma unroll
      for (int j = 0; j < 4; j++)
        acc[i][j] = __builtin_amdgcn_mfma_f32_16x16x32_bf16(af[i], bf[j], acc[i][j], 0, 0, 0);
  }
  const int nb = n0 + wn * 64;       // 64-aligned -> sel, h wave-uniform
  const int sel = nb >> 10;
  const int h = (nb >> 6) & 15;
  const float* bias = sel == 0 ? bq : (sel == 1 ? bk : bv);
  const int mbase = m0 + wm * 64;
  const int bb = mbase >> 11;
  const size_t bh = (size_t)(bb * N_HEADS + h);
  if (sel == 2) {
    // V: transpose 64x64 C-tile through wave-private LDS -> coalesced 16B stores (fp16)
    unsigned short* vs = &Stage[w][0];
    const size_t vbase = bh * (32 * 4096) + (size_t)((mbase >> 6) & 31) * 4096;
    const int e8 = lane >> 3, ch = lane & 7;
#pragma unroll
    for (int j = 0; j < 4; j++) {
      float be = bias[h * 64 + j * 16 + l16];
#pragma unroll
      for (int i = 0; i < 4; i++)
#pragma unroll
        for (int r = 0; r < 4; r++)
          vs[l16 * 72 + i * 16 + quad * 4 + r] = f2h(acc[i][j][r] + be);
      // wave-private, DS in-order: no barrier
#pragma unroll
      for (int rd = 0; rd < 2; rd++) {
        int er = rd * 8 + e8;
        short8 val = *(const short8*)(vs + er * 72 + ch * 8);
        *(short8*)(Vtb + vbase + (size_t)(j * 16 + er) * 64 + ch * 8) = val;
      }
    }
  } else {
    // Q/K: stage [s][e] j-slice (64x16, stride 18) in wave-private LDS -> b128 stores
    unsigned short* st = &Stage[w][0];
    unsigned short* dst = (sel == 0) ? Qb : Kb;
    const float qsc = (sel == 0) ? SC_LOG2E : 1.0f;
    const size_t rowbase = bh * SEQ + (mbase & (SEQ - 1));
    const int r2 = lane >> 1, c2 = lane & 1;
#pragma unroll
    for (int j = 0; j < 4; j++) {
      float be = bias[h * 64 + j * 16 + l16];
#pragma unroll
      for (int i = 0; i < 4; i++)
#pragma unroll
        for (int r = 0; r < 4; r++)
          st[(i * 16 + quad * 4 + r) * 18 + l16] = f2bf((acc[i][j][r] + be) * qsc);
#pragma unroll
      for (int p = 0; p < 2; p++) {
        int row = p * 32 + r2;
        short8 val = *(const short8*)(st + row * 18 + c2 * 8);
        *(short8*)(dst + (rowbase + row) * HEAD_DIM + j * 16 + c2 * 8) = val;
      }
    }
  }
}

// ---- flash attention v9b: 4-wave 128-row blocks (32 q-rows/wave), K/V LDS
// double-buffer, register-resident P, PAIRED PV via mfma_f32_16x16x32_f16.
// V staged with column perm t -> t' so paired P A-frag k-order matches. ----
__global__ __launch_bounds__(256) void attn_kernel(const unsigned short* __restrict__ Q,
                                                   const unsigned short* __restrict__ K,
                                                   const unsigned short* __restrict__ Vt,
                                                   unsigned short* __restrict__ concat) {
  __shared__ __align__(16) unsigned short Ks0[64 * 72], Ks1[64 * 72];
  __shared__ __align__(16) unsigned short Vs0[64 * 72], Vs1[64 * 72];
  const int b = blockIdx.z, h = blockIdx.y;
  const int tid = threadIdx.x;
  const int lane = tid & 63, w = tid >> 6;
  const int l16 = lane & 15, quad = lane >> 4;
  const size_t bh = (size_t)(b * N_HEADS + h);
  const int q0 = blockIdx.x * 128 + w * 32;
  float4_t z = {0.f, 0.f, 0.f, 0.f};

  // Q B-frags: B[k=e][n=q], lane n=l16 (pre-scaled by log2e/8)
  short8 aq[2][2];
#pragma unroll
  for (int rg = 0; rg < 2; rg++)
#pragma unroll
    for (int hf = 0; hf < 2; hf++)
      aq[rg][hf] = *(const short8*)(Q + (bh * SEQ + q0 + rg * 16 + l16) * HEAD_DIM + hf * 32 + quad * 8);

  // K staging: row = tid>>2 (64 rows), chunks (tid&3)*8 and +32 (natural layout)
  const int krow = tid >> 2, kch = (tid & 3) * 8;
  const unsigned short* kg = K + (bh * SEQ + krow) * HEAD_DIM + kch;
  const int ktw = krow * 72 + kch;
  // V staging: e-row = tid>>2, t-group vt0 = (tid&3)*16 (+8); perm t->t'
  const int vt0 = (tid & 3) * 16, vt1 = vt0 + 8;
  const unsigned short* vg = Vt + bh * (32 * 4096) + krow * 64 + vt0;
  const int tp0 = ((vt0 >> 5) << 5) + (((vt0 >> 2) & 3) << 3) + (((vt0 >> 4) & 1) << 2);
  const int tp1 = ((vt1 >> 5) << 5) + (((vt1 >> 2) & 3) << 3) + (((vt1 >> 4) & 1) << 2);
  const int vtw0 = krow * 72 + tp0, vtw1 = krow * 72 + tp1;

  float4_t o[2][4];
#pragma unroll
  for (int rg = 0; rg < 2; rg++)
#pragma unroll
    for (int ne = 0; ne < 4; ne++) o[rg][ne] = z;
  float lsp[2] = {0.f, 0.f};

  short8 kreg0 = *(const short8*)kg;
  short8 kreg1 = *(const short8*)(kg + 32);
  short8 vreg0 = *(const short8*)vg;
  short8 vreg1 = *(const short8*)(vg + 8);
  kg += 4096; vg += 4096;

  auto step = [&](unsigned short* kb, unsigned short* vb, int itv) {
    *(short8*)(kb + ktw) = kreg0;
    *(short8*)(kb + ktw + 32) = kreg1;
    // V: each 8-t chunk splits into two 4-t runs 8 apart in t'
    svec4 a0 = {vreg0[0], vreg0[1], vreg0[2], vreg0[3]};
    svec4 a1 = {vreg0[4], vreg0[5], vreg0[6], vreg0[7]};
    svec4 b0 = {vreg1[0], vreg1[1], vreg1[2], vreg1[3]};
    svec4 b1 = {vreg1[4], vreg1[5], vreg1[6], vreg1[7]};
    *(svec4*)(vb + vtw0) = a0;
    *(svec4*)(vb + vtw0 + 8) = a1;
    *(svec4*)(vb + vtw1) = b0;
    *(svec4*)(vb + vtw1 + 8) = b1;
    __syncthreads();
    if (itv < 31) {
      kreg0 = *(const short8*)kg;
      kreg1 = *(const short8*)(kg + 32);
      vreg0 = *(const short8*)vg;
      vreg1 = *(const short8*)(vg + 8);
      kg += 4096; vg += 4096;
    }
#pragma unroll
    for (int p = 0; p < 2; p++) {
      // QK for the pair's two 16-t tiles
      float4_t s[2][2];  // [tcl][rg]
#pragma unroll
      for (int tcl = 0; tcl < 2; tcl++) {
        int tc = 2 * p + tcl;
        short8 kf0 = *(const short8*)(kb + (tc * 16 + l16) * 72 + quad * 8);
        short8 kf1 = *(const short8*)(kb + (tc * 16 + l16) * 72 + 32 + quad * 8);
#pragma unroll
        for (int rg = 0; rg < 2; rg++) {
          s[tcl][rg] = __builtin_amdgcn_mfma_f32_16x16x32_bf16(kf0, aq[rg][0], z, 0, 0, 0);
          s[tcl][rg] = __builtin_amdgcn_mfma_f32_16x16x32_bf16(kf1, aq[rg][1], s[tcl][rg], 0, 0, 0);
        }
      }
      // V B-frags (f16, k=quad*8+j over the pair's 32 t')
      half8 vf[4];
#pragma unroll
      for (int ne = 0; ne < 4; ne++)
        vf[ne] = *(const half8*)(vb + (ne * 16 + l16) * 72 + p * 32 + quad * 8);
#pragma unroll
      for (int rg = 0; rg < 2; rg++) {
        float pv[8];
#pragma unroll
        for (int r = 0; r < 4; r++) {
          pv[r]     = __builtin_amdgcn_exp2f(s[0][rg][r]);
          pv[4 + r] = __builtin_amdgcn_exp2f(s[1][rg][r]);
        }
        lsp[rg] += ((pv[0] + pv[1]) + (pv[2] + pv[3])) + ((pv[4] + pv[5]) + (pv[6] + pv[7]));
        half8 pa = {(_Float16)pv[0], (_Float16)pv[1], (_Float16)pv[2], (_Float16)pv[3],
                    (_Float16)pv[4], (_Float16)pv[5], (_Float16)pv[6], (_Float16)pv[7]};
#pragma unroll
        for (int ne = 0; ne < 4; ne++)
          o[rg][ne] = __builtin_amdgcn_mfma_f32_16x16x32_f16(pa, vf[ne], o[rg][ne], 0, 0, 0);
      }
    }
  };

  for (int it2 = 0; it2 < 16; ++it2) {
    step(Ks0, Vs0, 2 * it2);
    step(Ks1, Vs1, 2 * it2 + 1);
  }

  // row-sums: lsp holds per-quad t-partials for q=l16; reduce across quads
  float lsf[2];
#pragma unroll
  for (int rg = 0; rg < 2; rg++) {
    float v = lsp[rg];
    v += __shfl_xor(v, 16, 64);
    v += __shfl_xor(v, 32, 64);
    lsf[rg] = v;
  }
#pragma unroll
  for (int rg = 0; rg < 2; rg++) {
#pragma unroll
    for (int r = 0; r < 4; r++) {
      float li = 1.0f / __shfl(lsf[rg], quad * 4 + r, 64);
      int sr = q0 + rg * 16 + quad * 4 + r;
#pragma unroll
      for (int ne = 0; ne < 4; ne++)
        concat[((size_t)(b * SEQ + sr)) * D_MODEL + h * 64 + ne * 16 + l16] = f2bf(o[rg][ne][r] * li);
    }
  }
}

// ---- out = concat @ Wp^T + bp (f32 out), 128x64 tiles -> 512 blocks ----
__global__ __launch_bounds__(256) void out_gemm(const unsigned short* __restrict__ cb,
                                                const unsigned short* __restrict__ Wpb,
                                                const float* __restrict__ bp,
                                                float* __restrict__ out) {
  __shared__ unsigned short As[128 * 32], Bs[64 * 32];
  const int m0 = blockIdx.x * 128, n0 = blockIdx.y * 64;
  const int lane = threadIdx.x & 63, w = threadIdx.x >> 6;
  const int l16 = lane & 15, quad = lane >> 4;
  const int ldrow = lane >> 2, ldcol = (lane & 3) * 8;
  const unsigned short* ga0 = cb + (size_t)(m0 + w * 32 + ldrow) * D_MODEL + ldcol;
  const unsigned short* ga1 = ga0 + 16 * D_MODEL;
  const unsigned short* gb0 = Wpb + (size_t)(n0 + w * 16 + ldrow) * D_MODEL + ldcol;
  unsigned short* lA0 = As + (w * 2 + 0) * 512;
  unsigned short* lA1 = As + (w * 2 + 1) * 512;
  unsigned short* lB0 = Bs + w * 512;
  float4_t acc[2][4];
  float4_t z = {0.f, 0.f, 0.f, 0.f};
#pragma unroll
  for (int i = 0; i < 2; i++)
#pragma unroll
    for (int j = 0; j < 4; j++) acc[i][j] = z;
  for (int k0 = 0; k0 < D_MODEL; k0 += 32) {
    __syncthreads();
    gl_lds16(ga0 + k0, lA0);
    gl_lds16(ga1 + k0, lA1);
    gl_lds16(gb0 + k0, lB0);
    __syncthreads();
    short8 af[2], bf[4];
#pragma unroll
    for (int i = 0; i < 2; i++) af[i] = *(const short8*)&As[(w * 32 + i * 16 + l16) * 32 + quad * 8];
#pragma unroll
    for (int j = 0; j < 4; j++) bf[j] = *(const short8*)&Bs[(j * 16 + l16) * 32 + quad * 8];
#pragma unroll
    for (int i = 0; i < 2; i++)
#pragma unroll
      for (int j = 0; j < 4; j++)
        acc[i][j] = __builtin_amdgcn_mfma_f32_16x16x32_bf16(af[i], bf[j], acc[i][j], 0, 0, 0);
  }
#pragma unroll
  for (int i = 0; i < 2; i++)
#pragma unroll
    for (int j = 0; j < 4; j++)
#pragma unroll
      for (int r = 0; r < 4; r++) {
        int m = m0 + w * 32 + i * 16 + quad * 4 + r;
        int oc = n0 + j * 16 + l16;
        out[(size_t)m * D_MODEL + oc] = acc[i][j][r] + bp[oc];
      }
}

extern "C" void kernel_launch(void* const* d_in, const int* in_sizes, int n_in,
                              void* d_out, int out_size, void* d_ws, size_t ws_size,
                              hipStream_t stream) {
  const float* x  = (const float*)d_in[0];
  const float* Wq = (const float*)d_in[1];
  const float* Wk = (const float*)d_in[2];
  const float* Wv = (const float*)d_in[3];
  const float* bq = (const float*)d_in[4];
  const float* bk = (const float*)d_in[5];
  const float* bv = (const float*)d_in[6];
  const float* Wp = (const float*)d_in[7];
  const float* bp = (const float*)d_in[8];
  float* out = (float*)d_out;

  char* ws = (char*)d_ws;
  size_t off = 0;
  auto alloc = [&](size_t bytes) -> void* {
    void* p = ws + off;
    off += (bytes + 255) & ~(size_t)255;
    return p;
  };
  unsigned short* xb   = (unsigned short*)alloc((size_t)M_ROWS * D_MODEL * 2);
  unsigned short* Wall = (unsigned short*)alloc((size_t)NQKV * D_MODEL * 2);
  unsigned short* Wpb  = (unsigned short*)alloc((size_t)D_MODEL * D_MODEL * 2);
  unsigned short* Qb   = (unsigned short*)alloc((size_t)B_SZ * N_HEADS * SEQ * HEAD_DIM * 2);
  unsigned short* Kb   = (unsigned short*)alloc((size_t)B_SZ * N_HEADS * SEQ * HEAD_DIM * 2);
  unsigned short* Vtb  = (unsigned short*)alloc((size_t)B_SZ * N_HEADS * SEQ * HEAD_DIM * 2);
  unsigned short* cbuf = (unsigned short*)alloc((size_t)B_SZ * SEQ * D_MODEL * 2);

  prep<<<17408, 256, 0, stream>>>(x, Wp, Wq, Wk, Wv, xb, Wpb, Wall);

  qkv_gemm<<<dim3(M_ROWS / 128, NQKV / 128), 256, 0, stream>>>(xb, Wall, bq, bk, bv, Qb, Kb, Vtb);

  attn_kernel<<<dim3(SEQ / 128, N_HEADS, B_SZ), 256, 0, stream>>>(Qb, Kb, Vtb, cbuf);

  out_gemm<<<dim3(M_ROWS / 128, D_MODEL / 64), 256, 0, stream>>>(cbuf, Wpb, bp, out);
}